// Round 10
// baseline (371.679 us; speedup 1.0000x reference)
//
#include <hip/hip_runtime.h>

#define S_TOTAL 17064
#define NB 16
#define NC 80

#define L0_BPB 125                               // (80*12800 floats)/8192 per image
#define L1_BPB 32                                // 256000/8192 = 31.25 -> 32 (last partial)
#define L0_BLOCKS (NB * L0_BPB)                  // 2000
#define L1_BLOCKS (NB * L1_BPB)                  // 512
#define MF_BPB 15                                // lvls 2,3,4 x 5 class-groups of 16
#define MF_BLOCKS (NB * MF_BPB)                  // 240
#define PB_BLOCKS (NB * 17)                      // 272
#define B_L1 (L0_BLOCKS)                         // 2000
#define B_MF (L0_BLOCKS + L1_BLOCKS)             // 2512
#define B_PB (B_MF + MF_BLOCKS)                  // 2752
#define TOTAL_BLOCKS (B_PB + PB_BLOCKS)          // 3024

typedef float vfloat4 __attribute__((ext_vector_type(4)));

struct Ptrs {
    const float* cls[5];
    const float* cnt[5];
    const float* reg[5];
    const float* cnt_t;   // [B,S,1]
    const float* reg_t;   // [B,S,4]
    const int*   cls_t;   // [B,S,1]
    float*       ws;      // [0:16) cls, [16:32) cnt, [32:48) reg, [48:64) pos, [64] counter
    float*       out;
};

__device__ __forceinline__ float focal_term(float x, bool o) {
    const float xs = o ? x : -x;            // p_t = sigmoid(xs)
    const float af = o ? 0.25f : 0.75f;
    const float em = __expf(-xs);
    const float pt = 1.0f / (1.0f + em);
    const float q  = em * pt;               // 1 - p_t
    return af * q * q * __logf(1.0f + em);  // -af*(1-pt)^2*log(pt)
}

__device__ __forceinline__ float giou_term(float pl, float pt_, float pr, float pb,
                                           float tl, float tt, float tr, float tb) {
    const float overlap = fmaxf(fminf(pr, tr) + fminf(pl, tl), 0.0f) *
                          fmaxf(fminf(pb, tb) + fminf(pt_, tt), 0.0f);
    const float area1 = (pr + pl) * (pb + pt_);
    const float area2 = (tr + tl) * (tb + tt);
    const float uni = area1 + area2 - overlap;
    const float iou = overlap / uni;
    const float ga = fmaxf(fmaxf(pr, tr) + fmaxf(pl, tl), 0.0f) *
                     fmaxf(fmaxf(pb, tb) + fmaxf(pt_, tt), 0.0f);
    const float giou = iou - (ga - uni) / fmaxf(ga, 1e-10f);
    return 1.0f - giou;
}

__device__ __forceinline__ float bce_term(float x, float t) {
    return fmaxf(x, 0.0f) - x * t + __logf(1.0f + __expf(-fabsf(x)));
}

// Wave reads 8 KiB CONTIGUOUS of one image's [C,HW] cls plane (8 x 256-float
// segments, ascending addresses), recovering class/s per lane via const-div.
// Rows are multiples of 4 floats and flat is a multiple of 4, so a float4
// never straddles a class-row boundary.
template<int HW, int OFF>
__device__ __forceinline__ float focal_stream(const float* __restrict__ clsb,  // + b*NC*HW
                                              const int* __restrict__ tb,      // cls_t + b*S + OFF
                                              int plane_base, int lane) {
    unsigned cbase[8];
    const int* taddr[8];
    #pragma unroll
    for (int j = 0; j < 8; ++j) {
        const unsigned flat = (unsigned)(plane_base + j * 256 + lane * 4);
        const unsigned c = flat / (unsigned)HW;          // magic-mul, compile-time HW
        const unsigned s = flat - c * (unsigned)HW;
        cbase[j] = c + 1;
        taddr[j] = tb + s;
    }
    vfloat4 v[8];
    int4 tq[8];
    #pragma unroll
    for (int j = 0; j < 8; ++j)
        v[j] = *(const vfloat4*)(clsb + plane_base + j * 256 + lane * 4);
    #pragma unroll
    for (int j = 0; j < 8; ++j)
        tq[j] = *(const int4*)(taddr[j]);

    float a0 = 0.f, a1 = 0.f, a2 = 0.f, a3 = 0.f;
    #pragma unroll
    for (int j = 0; j < 8; ++j) {
        const int cp1 = (int)cbase[j];
        a0 += focal_term(v[j].x, tq[j].x == cp1);
        a1 += focal_term(v[j].y, tq[j].y == cp1);
        a2 += focal_term(v[j].z, tq[j].z == cp1);
        a3 += focal_term(v[j].w, tq[j].w == cp1);
    }
    return (a0 + a1) + (a2 + a3);
}

__global__ __launch_bounds__(256) void fcos_main(Ptrs p) {
    const int bid = blockIdx.x;
    const int tid = threadIdx.x;
    const int wv  = tid >> 6;
    const int ln  = tid & 63;

    float cls_acc = 0.f, cnt_acc = 0.f, reg_acc = 0.f, pos_acc = 0.f;
    int b;

    if (bid < B_L1) {
        // ---- lvl0 main: 32-KiB contiguous chunk of image b's [80,12800] plane ----
        b = bid / L0_BPB;
        const int bx = bid - b * L0_BPB;
        const int plane_base = bx * 8192 + wv * 2048;
        cls_acc = focal_stream<12800, 0>(p.cls[0] + (size_t)b * NC * 12800,
                                         p.cls_t + b * S_TOTAL + 0, plane_base, ln);
    } else if (bid < B_MF) {
        // ---- lvl1 main: [80,3200] plane = 256000 floats; last block partial ----
        const int i = bid - B_L1;
        b = i >> 5;
        const int bx = i & 31;
        const int plane_base = bx * 8192 + wv * 2048;
        if (plane_base < 256000)
            cls_acc = focal_stream<3200, 12800>(p.cls[1] + (size_t)b * NC * 3200,
                                                p.cls_t + b * S_TOTAL + 12800, plane_base, ln);
    } else if (bid < B_PB) {
        // ---- lvl2/3/4 focal: (lvl, class-group of 16), thread = quad ----
        const int i = bid - B_MF;
        b = i / MF_BPB;
        const int r = i - b * MF_BPB;
        const int lsel = r / 5;                   // 0->lvl2 1->lvl3 2->lvl4
        const int cg   = r - lsel * 5;
        const int lvl  = lsel + 2;
        const int HWs[3] = {800, 208, 56};
        const int NQs[3] = {200, 52, 14};
        const int OFs[3] = {16000, 16800, 17008};
        const int hw = HWs[lsel], nq = NQs[lsel], off = OFs[lsel];

        const bool active = (tid < nq);
        const int qc = active ? tid : 0;
        const int s0 = qc << 2;
        const int4 tq = *(const int4*)(p.cls_t + b * S_TOTAL + off + s0);
        const float* cp = p.cls[lvl] + (size_t)((b * NC + cg * 16) * hw + s0);

        vfloat4 v[16];
        #pragma unroll
        for (int j = 0; j < 16; ++j)
            v[j] = *(const vfloat4*)(cp + (size_t)(j * hw));
        float a0 = 0.f, a1 = 0.f, a2 = 0.f, a3 = 0.f;
        #pragma unroll
        for (int j = 0; j < 16; ++j) {
            const int cp1 = cg * 16 + j + 1;
            a0 += focal_term(v[j].x, tq.x == cp1);
            a1 += focal_term(v[j].y, tq.y == cp1);
            a2 += focal_term(v[j].z, tq.z == cp1);
            a3 += focal_term(v[j].w, tq.w == cp1);
        }
        cls_acc = active ? ((a0 + a1) + (a2 + a3)) : 0.f;
    } else {
        // ---- cnt BCE + GIoU (R5-proven) ----
        const int i = bid - B_PB;
        b = i / 17;
        const int chunk = i - b * 17;
        const int fq = chunk * 256 + tid;

        int lvl, qbase, hw, off;
        if (fq < 3200)      { lvl = 0; qbase = 0;    hw = 12800; off = 0;     }
        else if (fq < 4000) { lvl = 1; qbase = 3200; hw = 3200;  off = 12800; }
        else if (fq < 4200) { lvl = 2; qbase = 4000; hw = 800;   off = 16000; }
        else if (fq < 4252) { lvl = 3; qbase = 4200; hw = 208;   off = 16800; }
        else                { lvl = 4; qbase = 4252; hw = 56;    off = 17008; }

        if (fq < 4266) {
            const int s0  = (fq - qbase) << 2;
            const int gs0 = b * S_TOTAL + off + s0;
            const float4 xc  = *(const float4*)(p.cnt[lvl] + (size_t)(b * hw + s0));
            const float4 tC  = *(const float4*)(p.cnt_t + gs0);
            const float* rp  = p.reg[lvl] + (size_t)(b * 4 * hw + s0);
            const float4 pl  = *(const float4*)(rp);
            const float4 pt_ = *(const float4*)(rp + (size_t)hw);
            const float4 pr  = *(const float4*)(rp + (size_t)(2 * hw));
            const float4 pb_ = *(const float4*)(rp + (size_t)(3 * hw));
            const float4 t0  = *(const float4*)(p.reg_t + (size_t)(gs0 + 0) * 4);
            const float4 t1  = *(const float4*)(p.reg_t + (size_t)(gs0 + 1) * 4);
            const float4 t2  = *(const float4*)(p.reg_t + (size_t)(gs0 + 2) * 4);
            const float4 t3  = *(const float4*)(p.reg_t + (size_t)(gs0 + 3) * 4);

            const float m0 = (tC.x > -1.0f) ? 1.0f : 0.0f;
            const float m1 = (tC.y > -1.0f) ? 1.0f : 0.0f;
            const float m2 = (tC.z > -1.0f) ? 1.0f : 0.0f;
            const float m3 = (tC.w > -1.0f) ? 1.0f : 0.0f;
            pos_acc = m0 + m1 + m2 + m3;
            cnt_acc = bce_term(xc.x, tC.x) * m0 + bce_term(xc.y, tC.y) * m1 +
                      bce_term(xc.z, tC.z) * m2 + bce_term(xc.w, tC.w) * m3;
            reg_acc = giou_term(pl.x, pt_.x, pr.x, pb_.x, t0.x, t0.y, t0.z, t0.w) * m0 +
                      giou_term(pl.y, pt_.y, pr.y, pb_.y, t1.x, t1.y, t1.z, t1.w) * m1 +
                      giou_term(pl.z, pt_.z, pr.z, pb_.z, t2.x, t2.y, t2.z, t2.w) * m2 +
                      giou_term(pl.w, pt_.w, pr.w, pb_.w, t3.x, t3.y, t3.z, t3.w) * m3;
        }
    }

    // ---- block reduction ----
    #pragma unroll
    for (int d = 32; d; d >>= 1) {
        cls_acc += __shfl_down(cls_acc, d);
        cnt_acc += __shfl_down(cnt_acc, d);
        reg_acc += __shfl_down(reg_acc, d);
        pos_acc += __shfl_down(pos_acc, d);
    }

    __shared__ float red[4][4];
    if (ln == 0) {
        red[0][wv] = cls_acc;
        red[1][wv] = cnt_acc;
        red[2][wv] = reg_acc;
        red[3][wv] = pos_acc;
    }
    __syncthreads();
    if (tid == 0) {
        atomicAdd(&p.ws[b], red[0][0] + red[0][1] + red[0][2] + red[0][3]);
        if (bid >= B_PB) {
            atomicAdd(&p.ws[16 + b], red[1][0] + red[1][1] + red[1][2] + red[1][3]);
            atomicAdd(&p.ws[32 + b], red[2][0] + red[2][1] + red[2][2] + red[2][3]);
            atomicAdd(&p.ws[48 + b], red[3][0] + red[3][1] + red[3][2] + red[3][3]);
        }
    }

    // ---- last-block finalize ----
    __shared__ int is_last;
    if (tid == 0) {
        __threadfence();
        const int old = __hip_atomic_fetch_add((int*)(p.ws + 64), 1,
                            __ATOMIC_ACQ_REL, __HIP_MEMORY_SCOPE_AGENT);
        is_last = (old == TOTAL_BLOCKS - 1) ? 1 : 0;
    }
    __syncthreads();
    if (is_last && tid < 64) {
        __threadfence();
        float l0 = 0.f, l1 = 0.f, l2 = 0.f;
        if (tid < NB) {
            const float np = fmaxf(__hip_atomic_load(&p.ws[48 + tid],
                __ATOMIC_RELAXED, __HIP_MEMORY_SCOPE_AGENT), 1.0f);
            l0 = __hip_atomic_load(&p.ws[tid],
                __ATOMIC_RELAXED, __HIP_MEMORY_SCOPE_AGENT) / np;
            l1 = __hip_atomic_load(&p.ws[16 + tid],
                __ATOMIC_RELAXED, __HIP_MEMORY_SCOPE_AGENT) / np;
            l2 = __hip_atomic_load(&p.ws[32 + tid],
                __ATOMIC_RELAXED, __HIP_MEMORY_SCOPE_AGENT) / np;
        }
        #pragma unroll
        for (int d = 32; d; d >>= 1) {
            l0 += __shfl_down(l0, d);
            l1 += __shfl_down(l1, d);
            l2 += __shfl_down(l2, d);
        }
        if (tid == 0) {
            l0 *= (1.0f / NB);
            l1 *= (1.0f / NB);
            l2 *= (1.0f / NB);
            p.out[0] = l0;
            p.out[1] = l1;
            p.out[2] = l2;
            p.out[3] = l0 + l1 + l2;
        }
    }
}

extern "C" void kernel_launch(void* const* d_in, const int* in_sizes, int n_in,
                              void* d_out, int out_size, void* d_ws, size_t ws_size,
                              hipStream_t stream) {
    Ptrs p;
    for (int i = 0; i < 5; ++i) {
        p.cls[i] = (const float*)d_in[3 * i + 0];
        p.cnt[i] = (const float*)d_in[3 * i + 1];
        p.reg[i] = (const float*)d_in[3 * i + 2];
    }
    p.cnt_t = (const float*)d_in[15];
    p.reg_t = (const float*)d_in[16];
    p.cls_t = (const int*)  d_in[17];
    p.ws    = (float*)d_ws;
    p.out   = (float*)d_out;

    (void)hipMemsetAsync(d_ws, 0, 68 * sizeof(float), stream);  // sums + counter

    fcos_main<<<dim3(TOTAL_BLOCKS, 1, 1), 256, 0, stream>>>(p);
}